// Round 6
// baseline (640.379 us; speedup 1.0000x reference)
//
#include <hip/hip_runtime.h>
#include <hip/hip_cooperative_groups.h>
namespace cg = cooperative_groups;

#define HH 128
#define WW 128
#define NPIX 16384
#define NC 32
#define NO 32
#define KS 9
#define TAPS 81
#define DIL 2
#define PAD 8
#define SMAX 27.6310211159f   // s <= SMAX <=> exp(-0.5 s) >= 1e-6; dropped-tap bound ~1.4e-5 << tol
#define NW (NO * NC * TAPS)   // 82944
#define GRID 1024             // coop grid: 4 blocks/CU x 256 CUs (verified by coop launch)
#define SEGCAP 1280           // 256 threads x 5 taps: per-block segment can NEVER overflow
#define CAP 262144            // fallback-path list capacity

// ---------------------------------------------------------------------------
// seg_sparse: process one block-private list segment. 8 entries at a time,
// 32 lanes per entry (o = lane&31). Weights from Wt[tap][o][c] -> per-lane
// contiguous 32 floats = 8x dwordx4; in[c][q] broadcast across the 32 lanes.
// Accumulate via f32 atomics (target pre-written / atomic-only -> order-free).
// ---------------------------------------------------------------------------
__device__ __forceinline__ void seg_sparse(
    const float* __restrict__ in, const float* __restrict__ Wt,
    const uint2* __restrict__ seg, unsigned n, float* __restrict__ outp,
    int tid)
{
    for (unsigned base = 0; base < n; base += 8) {
        unsigned e = base + ((unsigned)tid >> 5);
        if (e < n) {
            uint2 me = seg[e];
            int pix = (int)(me.x & 16383u);
            int T = (int)(me.x >> 14);
            float kv = __uint_as_float(me.y);
            int ii = T / KS, jj = T - KS * ii;
            int q = pix + (ii * DIL - PAD) * WW + (jj * DIL - PAD);
            int o = tid & 31;
            const float4* __restrict__ wp =
                (const float4*)(Wt + (T * NO + o) * NC);
            float t0 = 0.f, t1 = 0.f, t2 = 0.f, t3 = 0.f;
#pragma unroll
            for (int c4 = 0; c4 < 8; ++c4) {
                float4 w4 = wp[c4];
                t0 = fmaf(in[(4 * c4 + 0) * NPIX + q], w4.x, t0);
                t1 = fmaf(in[(4 * c4 + 1) * NPIX + q], w4.y, t1);
                t2 = fmaf(in[(4 * c4 + 2) * NPIX + q], w4.z, t2);
                t3 = fmaf(in[(4 * c4 + 3) * NPIX + q], w4.w, t3);
            }
            atomicAdd(&outp[o * NPIX + pix], kv * ((t0 + t1) + (t2 + t3)));
        }
    }
}

// ---------------------------------------------------------------------------
// fused_kernel (cooperative, ONE dispatch): rounds 1-5 showed ~20 us fixed
// cost PER DISPATCH regardless of kernel content -> collapse the whole op.
//   P0: every thread preps 5 non-center taps of one pixel (t0 = gtid>>14,
//       T = m<40?m:m+1 bijects onto the 80 non-center taps); live taps are
//       compacted into the block's PRIVATE list segment via an LDS counter
//       (no global counter -> no init-ordering hazard). Blocks also do role
//       work: [0,512) dense1 (exact center 1x1 conv, kv=1, LDS-staged W),
//       [512,640) zero d_out, [640,704) weight transpose -> [tap][o][c].
//   P1: block b consumes segment b -> atomic residual into h.
//   P2: dense2 (atomic, +bias) + sparse2 over all segments -> out.
// __threadfence() around each grid.sync() for cross-XCD L2 visibility (G16).
// ---------------------------------------------------------------------------
__global__ __launch_bounds__(256, 4) void fused_kernel(
    const float* __restrict__ x, const float* __restrict__ f,
    const float* __restrict__ W1, const float* __restrict__ b1,
    const float* __restrict__ W2, const float* __restrict__ b2,
    float* __restrict__ out, float* __restrict__ h,
    float* __restrict__ W1t, float* __restrict__ W2t,
    unsigned* __restrict__ cnts, uint2* __restrict__ list)
{
    cg::grid_group grid = cg::this_grid();
    const int bid = blockIdx.x;
    const int tid = threadIdx.x;
    __shared__ unsigned lcnt;
    __shared__ float wsm[4 * NC];

    if (tid == 0) lcnt = 0u;
    __syncthreads();

    // ---- P0a: prep (all 262144 threads, 5 taps each, same pix per thread)
    {
        const int gtid = bid * 256 + tid;
        const int pix = gtid & (NPIX - 1);
        const int t0 = gtid >> 14;            // 0..15, wave-uniform
        const int hh = pix >> 7, ww = pix & (WW - 1);
        float fc[NC];
#pragma unroll
        for (int c = 0; c < NC; ++c) fc[c] = f[c * NPIX + pix];
        unsigned live = 0u;
        float kv[5];                           // compile-time indexed only
#pragma unroll
        for (int k = 0; k < 5; ++k) {
            int m = t0 + 16 * k;               // 0..79
            int T = m < 40 ? m : m + 1;        // skip center tap 40
            int ii = T / KS, jj = T - KS * ii;
            int qh = hh + ii * DIL - PAD;
            int qw = ww + jj * DIL - PAD;
            bool valid = ((unsigned)qh < HH) & ((unsigned)qw < WW);
            int q = valid ? (qh * WW + qw) : pix;   // safe addr for masked lanes
            float s0 = 0.f, s1 = 0.f, s2 = 0.f, s3 = 0.f;
#pragma unroll
            for (int c4 = 0; c4 < 8; ++c4) {
                float d0 = f[(4 * c4 + 0) * NPIX + q] - fc[4 * c4 + 0];
                float d1 = f[(4 * c4 + 1) * NPIX + q] - fc[4 * c4 + 1];
                float d2 = f[(4 * c4 + 2) * NPIX + q] - fc[4 * c4 + 2];
                float d3 = f[(4 * c4 + 3) * NPIX + q] - fc[4 * c4 + 3];
                s0 = fmaf(d0, d0, s0); s1 = fmaf(d1, d1, s1);
                s2 = fmaf(d2, d2, s2); s3 = fmaf(d3, d3, s3);
            }
            float s = (s0 + s1) + (s2 + s3);
            // OOB taps contribute exactly 0 (x zero-padded) -> drop exactly.
            if (valid && (s <= SMAX)) {
                live |= 1u << k;
                kv[k] = __expf(-0.5f * s);
            }
        }
#pragma unroll
        for (int k = 0; k < 5; ++k)
            if (live & (1u << k)) {
                int m = t0 + 16 * k;
                int T = m < 40 ? m : m + 1;
                unsigned idx = atomicAdd(&lcnt, 1u);   // LDS atomic, fast
                list[bid * SEGCAP + idx] = make_uint2(
                    (unsigned)pix | ((unsigned)T << 14),
                    __float_as_uint(kv[k]));
            }
    }
    __syncthreads();
    if (tid == 0) cnts[bid] = lcnt;            // unconditional: kills ws poison

    // ---- P0b: role work
    if (bid < 512) {                           // dense1 -> h (exact center)
        const int o0 = (bid >> 6) * 4;
        const int pix = (bid & 63) * 256 + tid;
        if (tid < 128)
            wsm[tid] = W1[((o0 + (tid >> 5)) * NC + (tid & 31)) * TAPS + 40];
        __syncthreads();
        float x0[NC];
#pragma unroll
        for (int c = 0; c < NC; ++c) x0[c] = x[c * NPIX + pix];
        float a0 = 0.f, a1 = 0.f, a2 = 0.f, a3 = 0.f;
#pragma unroll
        for (int c = 0; c < NC; ++c) {
            float xv = x0[c];
            a0 = fmaf(xv, wsm[0 * NC + c], a0);
            a1 = fmaf(xv, wsm[1 * NC + c], a1);
            a2 = fmaf(xv, wsm[2 * NC + c], a2);
            a3 = fmaf(xv, wsm[3 * NC + c], a3);
        }
        h[(o0 + 0) * NPIX + pix] = a0 + b1[o0 + 0];
        h[(o0 + 1) * NPIX + pix] = a1 + b1[o0 + 1];
        h[(o0 + 2) * NPIX + pix] = a2 + b1[o0 + 2];
        h[(o0 + 3) * NPIX + pix] = a3 + b1[o0 + 3];
    } else if (bid < 640) {                    // zero d_out for P2 atomics
        float4 z = make_float4(0.f, 0.f, 0.f, 0.f);
        for (int t = (bid - 512) * 256 + tid; t < (NO * NPIX) / 4;
             t += 128 * 256)
            ((float4*)out)[t] = z;
    } else if (bid < 704) {                    // W transpose -> [tap][o][c]
        for (int t = (bid - 640) * 256 + tid; t < NW; t += 64 * 256) {
            int o = t / (NC * TAPS);
            int r = t - o * (NC * TAPS);
            int c = r / TAPS;
            int tap = r - c * TAPS;
            int d = (tap * NO + o) * NC + c;
            W1t[d] = W1[t];
            W2t[d] = W2[t];
        }
    }

    __threadfence();
    grid.sync();
    __threadfence();

    // ---- P1: sparse residual of layer 1 into h (segment b by block b)
    seg_sparse(x, W1t, list + bid * SEGCAP, cnts[bid], h, tid);

    __threadfence();
    grid.sync();
    __threadfence();

    // ---- P2: dense2 (+bias, atomic) and sparse2 into pre-zeroed out
    if (bid < 512) {
        const int o0 = (bid >> 6) * 4;
        const int pix = (bid & 63) * 256 + tid;
        if (tid < 128)
            wsm[tid] = W2[((o0 + (tid >> 5)) * NC + (tid & 31)) * TAPS + 40];
        __syncthreads();
        float h0[NC];
#pragma unroll
        for (int c = 0; c < NC; ++c) h0[c] = h[c * NPIX + pix];
        float a0 = 0.f, a1 = 0.f, a2 = 0.f, a3 = 0.f;
#pragma unroll
        for (int c = 0; c < NC; ++c) {
            float hv = h0[c];
            a0 = fmaf(hv, wsm[0 * NC + c], a0);
            a1 = fmaf(hv, wsm[1 * NC + c], a1);
            a2 = fmaf(hv, wsm[2 * NC + c], a2);
            a3 = fmaf(hv, wsm[3 * NC + c], a3);
        }
        atomicAdd(&out[(o0 + 0) * NPIX + pix], a0 + b2[o0 + 0]);
        atomicAdd(&out[(o0 + 1) * NPIX + pix], a1 + b2[o0 + 1]);
        atomicAdd(&out[(o0 + 2) * NPIX + pix], a2 + b2[o0 + 2]);
        atomicAdd(&out[(o0 + 3) * NPIX + pix], a3 + b2[o0 + 3]);
    } else {
        for (int s = bid - 512; s < GRID; s += 512)
            seg_sparse(h, W2t, list + s * SEGCAP, cnts[s], out, tid);
    }
}

// ===========================================================================
// Fallback path A (round-5 proven, 126.9 us): 4 classic dispatches.
// ===========================================================================
__global__ __launch_bounds__(64) void zero_cnt_kernel(unsigned* __restrict__ cnt)
{
    if (threadIdx.x == 0) *cnt = 0u;
}

__device__ __forceinline__ void sparse_body(
    const float* __restrict__ in, const float* __restrict__ Wt,
    const unsigned* __restrict__ cnt, const uint2* __restrict__ list,
    float* __restrict__ out, unsigned gid, unsigned stride)
{
    unsigned n = *cnt;
    if (n > CAP) n = CAP;
    const unsigned total = n * 32u;
    for (unsigned it = gid; it < total; it += stride) {
        unsigned e = it >> 5;
        int o = (int)(it & 31u);
        uint2 me = list[e];
        int pix = (int)(me.x & 16383u);
        int T = (int)(me.x >> 14);
        float kv = __uint_as_float(me.y);
        int ii = T / KS, jj = T - KS * ii;
        int q = pix + (ii * DIL - PAD) * WW + (jj * DIL - PAD);
        const float4* __restrict__ wp =
            (const float4*)(Wt + (T * NO + o) * NC);
        float t0 = 0.f, t1 = 0.f, t2 = 0.f, t3 = 0.f;
#pragma unroll
        for (int c4 = 0; c4 < 8; ++c4) {
            float4 w4 = wp[c4];
            t0 = fmaf(in[(4 * c4 + 0) * NPIX + q], w4.x, t0);
            t1 = fmaf(in[(4 * c4 + 1) * NPIX + q], w4.y, t1);
            t2 = fmaf(in[(4 * c4 + 2) * NPIX + q], w4.z, t2);
            t3 = fmaf(in[(4 * c4 + 3) * NPIX + q], w4.w, t3);
        }
        atomicAdd(&out[o * NPIX + pix], kv * ((t0 + t1) + (t2 + t3)));
    }
}

__global__ __launch_bounds__(256) void front_kernel(
    const float* __restrict__ x, const float* __restrict__ f,
    const float* __restrict__ W1, const float* __restrict__ W2,
    const float* __restrict__ b1,
    float* __restrict__ h, unsigned* __restrict__ cnt,
    uint2* __restrict__ list, float* __restrict__ W1t,
    float* __restrict__ W2t, float* __restrict__ outz)
{
    const int y = blockIdx.y;
    const int tid = threadIdx.x;

    if (y < 41) {
        const int pix = blockIdx.x * 256 + tid;
        const int hh = pix >> 7, ww = pix & (WW - 1);
        float fc[NC];
#pragma unroll
        for (int c = 0; c < NC; ++c) fc[c] = f[c * NPIX + pix];
#pragma unroll
        for (int u = 0; u < 2; ++u) {
            int T = 2 * y + u;
            if (T >= TAPS || T == 40) continue;
            int ii = T / KS, jj = T - KS * ii;
            int qh = hh + ii * DIL - PAD;
            int qw = ww + jj * DIL - PAD;
            bool valid = ((unsigned)qh < HH) & ((unsigned)qw < WW);
            int q = valid ? (qh * WW + qw) : pix;
            float s0 = 0.f, s1 = 0.f, s2 = 0.f, s3 = 0.f;
#pragma unroll
            for (int c4 = 0; c4 < 8; ++c4) {
                float d0 = f[(4 * c4 + 0) * NPIX + q] - fc[4 * c4 + 0];
                float d1 = f[(4 * c4 + 1) * NPIX + q] - fc[4 * c4 + 1];
                float d2 = f[(4 * c4 + 2) * NPIX + q] - fc[4 * c4 + 2];
                float d3 = f[(4 * c4 + 3) * NPIX + q] - fc[4 * c4 + 3];
                s0 = fmaf(d0, d0, s0); s1 = fmaf(d1, d1, s1);
                s2 = fmaf(d2, d2, s2); s3 = fmaf(d3, d3, s3);
            }
            float s = (s0 + s1) + (s2 + s3);
            if (valid && (s <= SMAX)) {
                unsigned idx = atomicAdd(cnt, 1u);
                if (idx < CAP)
                    list[idx] = make_uint2(
                        (unsigned)pix | ((unsigned)T << 14),
                        __float_as_uint(__expf(-0.5f * s)));
            }
        }
        return;
    }

    if (y < 49) {
        const int o0 = (y - 41) * 4;
        __shared__ float wsm[4 * NC];
        if (tid < 128) {
            int o = tid >> 5, c = tid & 31;
            wsm[tid] = W1[((o0 + o) * NC + c) * TAPS + 40];
        }
        __syncthreads();
        const int pix = blockIdx.x * 256 + tid;
        float x0[NC];
#pragma unroll
        for (int c = 0; c < NC; ++c) x0[c] = x[c * NPIX + pix];
        float a0 = 0.f, a1 = 0.f, a2 = 0.f, a3 = 0.f;
#pragma unroll
        for (int c = 0; c < NC; ++c) {
            float xv = x0[c];
            a0 = fmaf(xv, wsm[0 * NC + c], a0);
            a1 = fmaf(xv, wsm[1 * NC + c], a1);
            a2 = fmaf(xv, wsm[2 * NC + c], a2);
            a3 = fmaf(xv, wsm[3 * NC + c], a3);
        }
        h[(o0 + 0) * NPIX + pix] = a0 + b1[o0 + 0];
        h[(o0 + 1) * NPIX + pix] = a1 + b1[o0 + 1];
        h[(o0 + 2) * NPIX + pix] = a2 + b1[o0 + 2];
        h[(o0 + 3) * NPIX + pix] = a3 + b1[o0 + 3];
        return;
    }

    if (y == 49) {
        float4 z = make_float4(0.f, 0.f, 0.f, 0.f);
        for (int t = blockIdx.x * 256 + tid; t < (NO * NPIX) / 4; t += 64 * 256)
            ((float4*)outz)[t] = z;
        return;
    }

    for (int t = blockIdx.x * 256 + tid; t < NW; t += 64 * 256) {
        int o = t / (NC * TAPS);
        int r = t - o * (NC * TAPS);
        int c = r / TAPS;
        int tap = r - c * TAPS;
        int d = (tap * NO + o) * NC + c;
        W1t[d] = W1[t];
        W2t[d] = W2[t];
    }
}

__global__ __launch_bounds__(256) void sparse1_kernel(
    const float* __restrict__ x, const float* __restrict__ W1t,
    const unsigned* __restrict__ cnt, const uint2* __restrict__ list,
    float* __restrict__ h)
{
    sparse_body(x, W1t, cnt, list, h,
                blockIdx.x * 256 + threadIdx.x, gridDim.x * 256);
}

__global__ __launch_bounds__(256) void back_kernel(
    const float* __restrict__ h, const float* __restrict__ W2,
    const float* __restrict__ W2t, const float* __restrict__ b2,
    const unsigned* __restrict__ cnt, const uint2* __restrict__ list,
    float* __restrict__ out)
{
    const int y = blockIdx.y;
    const int tid = threadIdx.x;
    if (y < 8) {
        const int o0 = y * 4;
        __shared__ float wsm[4 * NC];
        if (tid < 128) {
            int o = tid >> 5, c = tid & 31;
            wsm[tid] = W2[((o0 + o) * NC + c) * TAPS + 40];
        }
        __syncthreads();
        const int pix = blockIdx.x * 256 + tid;
        float h0[NC];
#pragma unroll
        for (int c = 0; c < NC; ++c) h0[c] = h[c * NPIX + pix];
        float a0 = 0.f, a1 = 0.f, a2 = 0.f, a3 = 0.f;
#pragma unroll
        for (int c = 0; c < NC; ++c) {
            float hv = h0[c];
            a0 = fmaf(hv, wsm[0 * NC + c], a0);
            a1 = fmaf(hv, wsm[1 * NC + c], a1);
            a2 = fmaf(hv, wsm[2 * NC + c], a2);
            a3 = fmaf(hv, wsm[3 * NC + c], a3);
        }
        atomicAdd(&out[(o0 + 0) * NPIX + pix], a0 + b2[o0 + 0]);
        atomicAdd(&out[(o0 + 1) * NPIX + pix], a1 + b2[o0 + 1]);
        atomicAdd(&out[(o0 + 2) * NPIX + pix], a2 + b2[o0 + 2]);
        atomicAdd(&out[(o0 + 3) * NPIX + pix], a3 + b2[o0 + 3]);
        return;
    }
    sparse_body(h, W2t, cnt, list, out,
                blockIdx.x * 256 + tid, 64 * 256);
}

// ===========================================================================
// Fallback path B (tiny ws): fused per-layer, original W layout.
// ===========================================================================
#define CHUNK 27
#define NCHUNK 3
#define KMIN 1e-6f
__global__ __launch_bounds__(256) void pac_layer_fuse(
    const float* __restrict__ in, const float* __restrict__ f,
    const float* __restrict__ Wt, const float* __restrict__ bias,
    float* __restrict__ out)
{
    __shared__ float wl[NC * CHUNK * 8];
    const int og = blockIdx.y;
    const int pix = blockIdx.x * 256 + threadIdx.x;
    const int h = pix >> 7, w = pix & (WW - 1);
    float acc[8];
#pragma unroll
    for (int i = 0; i < 8; ++i) acc[i] = 0.f;
    float fc[NC];
#pragma unroll
    for (int c = 0; c < NC; ++c) fc[c] = f[c * NPIX + pix];
    for (int ch = 0; ch < NCHUNK; ++ch) {
        __syncthreads();
        for (int idx = threadIdx.x; idx < NC * CHUNK * 8; idx += 256) {
            int t = idx % CHUNK;
            int c = (idx / CHUNK) % NC;
            int o = idx / (CHUNK * NC);
            wl[(c * CHUNK + t) * 8 + o] =
                Wt[(og * 8 + o) * (NC * TAPS) + c * TAPS + ch * CHUNK + t];
        }
        __syncthreads();
        for (int t = 0; t < CHUNK; ++t) {
            int tap = ch * CHUNK + t;
            int qh = h + (tap / KS) * DIL - PAD;
            int qw = w + (tap % KS) * DIL - PAD;
            bool valid = ((unsigned)qh < HH) & ((unsigned)qw < WW);
            int q = qh * WW + qw;
            float s = 0.f;
#pragma unroll
            for (int c = 0; c < NC; ++c) {
                float fn = valid ? f[c * NPIX + q] : 0.f;
                float d = fn - fc[c];
                s = fmaf(d, d, s);
            }
            float kv = __expf(-0.5f * s);
            if (__all((kv < KMIN) | (!valid))) continue;
            const float* wpp = &wl[t * 8];
#pragma unroll 8
            for (int c = 0; c < NC; ++c) {
                float v = valid ? in[c * NPIX + q] : 0.f;
                v *= kv;
#pragma unroll
                for (int o = 0; o < 8; ++o)
                    acc[o] = fmaf(v, wpp[c * CHUNK * 8 + o], acc[o]);
            }
        }
    }
#pragma unroll
    for (int o = 0; o < 8; ++o)
        out[(og * 8 + o) * NPIX + pix] = acc[o] + bias[og * 8 + o];
}

// ---------------------------------------------------------------------------
extern "C" void kernel_launch(void* const* d_in, const int* in_sizes, int n_in,
                              void* d_out, int out_size, void* d_ws, size_t ws_size,
                              hipStream_t stream)
{
    (void)in_sizes; (void)n_in; (void)out_size;
    const float* x  = (const float*)d_in[0];
    const float* f  = (const float*)d_in[1];
    const float* W1 = (const float*)d_in[2];
    const float* b1 = (const float*)d_in[3];
    const float* W2 = (const float*)d_in[4];
    const float* b2 = (const float*)d_in[5];
    float* out = (float*)d_out;

    float* ws = (float*)d_ws;
    // shared layout (coop and fallback-A interpret tail differently)
    float* h   = ws;                               // NO*NPIX floats
    float* W1t = ws + NO * NPIX;                   // NW
    float* W2t = W1t + NW;                         // NW
    // coop tail:
    unsigned* cnts = (unsigned*)(W2t + NW);        // GRID u32
    uint2* seglist = (uint2*)(cnts + GRID);        // GRID*SEGCAP uint2
    const size_t need_coop =
        (size_t)(NO * NPIX + 2 * NW + GRID) * 4 + (size_t)GRID * SEGCAP * 8;
    // fallback-A tail:
    unsigned* cnt = (unsigned*)(W2t + NW);         // 16 u32 (pad)
    uint2* list = (uint2*)(cnt + 16);              // CAP uint2
    const size_t need_fb =
        (size_t)(NO * NPIX + 2 * NW + 16) * 4 + (size_t)CAP * 8;

    if (ws_size >= need_coop) {
        void* kargs[] = {
            (void*)&x, (void*)&f, (void*)&W1, (void*)&b1, (void*)&W2,
            (void*)&b2, (void*)&out, (void*)&h, (void*)&W1t, (void*)&W2t,
            (void*)&cnts, (void*)&seglist };
        hipError_t err = hipLaunchCooperativeKernel(
            fused_kernel, dim3(GRID), dim3(256), kargs, 0u, stream);
        if (err == hipSuccess) return;
        // else fall through to proven multi-dispatch path
    }
    if (ws_size >= need_fb) {
        zero_cnt_kernel<<<dim3(1), 64, 0, stream>>>(cnt);
        front_kernel<<<dim3(64, 51), 256, 0, stream>>>(
            x, f, W1, W2, b1, h, cnt, list, W1t, W2t, out);
        sparse1_kernel<<<dim3(128), 256, 0, stream>>>(x, W1t, cnt, list, h);
        back_kernel<<<dim3(64, 9), 256, 0, stream>>>(
            h, W2, W2t, b2, cnt, list, out);
    } else {
        float* hbuf = ws;
        pac_layer_fuse<<<dim3(64, 4), 256, 0, stream>>>(x, f, W1, b1, hbuf);
        pac_layer_fuse<<<dim3(64, 4), 256, 0, stream>>>(hbuf, f, W2, b2, out);
    }
}

// Round 7
// 120.252 us; speedup vs baseline: 5.3253x; 5.3253x over previous
//
#include <hip/hip_runtime.h>

#define HH 128
#define WW 128
#define NPIX 16384
#define NC 32
#define NO 32
#define KS 9
#define TAPS 81
#define DIL 2
#define PAD 8
#define SMAX 27.6310211159f   // s <= SMAX <=> exp(-0.5 s) >= 1e-6; dropped-tap bound ~1.4e-5 << tol
#define NW (NO * NC * TAPS)   // 82944
#define CAP 262144            // fallback-A list capacity

// ---------------------------------------------------------------------------
// Build an 81-bit live mask (M0: taps 0..63, M1: taps 64..80) for pixel P
// from the byte-owned mask2 rows (round-2 proven encoding: low byte j0..4,
// high byte j5..8 of a u16 per (i,pix)). Center bit is never set.
// ---------------------------------------------------------------------------
#define BUILD_MASK(P, M0, M1) do {                                          \
        M0 = 0ull; M1 = 0u;                                                 \
        _Pragma("unroll")                                                   \
        for (int i_ = 0; i_ < 7; ++i_) {                                    \
            unsigned v_ = mask2[i_ * NPIX + (P)];                           \
            unsigned m_ = (v_ & 31u) | (((v_ >> 8) & 15u) << 5);            \
            M0 |= (unsigned long long)m_ << (9 * i_);                       \
        }                                                                   \
        {                                                                   \
            unsigned v7_ = mask2[7 * NPIX + (P)];                           \
            unsigned v8_ = mask2[8 * NPIX + (P)];                           \
            unsigned m7_ = (v7_ & 31u) | (((v7_ >> 8) & 15u) << 5);         \
            unsigned m8_ = (v8_ & 31u) | (((v8_ >> 8) & 15u) << 5);         \
            M0 |= (unsigned long long)(m7_ & 1u) << 63;                     \
            M1 = (m7_ >> 1) | (m8_ << 8);                                   \
        }                                                                   \
    } while (0)

// ---------------------------------------------------------------------------
// D1 (front2): ONE dispatch, all mutually-independent roles by blockIdx.x:
//   [0,1152)    prep: (i, j-half) per block (round-2 proven byte-owned masks
//               + kbuf[T][pix] for live taps). 1152 blocks => 4.5 waves/SIMD.
//   [1152,1664) dense1: hd = b1 + W1[.,.,center]·x  (exact: kv_center = 1).
//               Center weights LDS-staged (parallel gather, broadcast reads).
//   [1664,1792) zero d_out (D2 accumulates with atomics only).
//   [1792,1873) M[T] = W2c @ W1[T]  (81 x 32x32 GEMM, both operands in LDS).
//   [1873,1937) transpose W1,W2 -> [tap][o][c] for per-lane dwordx4 gathers.
// No role reads another role's output -> no intra-dispatch ordering needed.
// ---------------------------------------------------------------------------
__global__ __launch_bounds__(256) void front2_kernel(
    const float* __restrict__ x, const float* __restrict__ f,
    const float* __restrict__ W1, const float* __restrict__ W2,
    const float* __restrict__ b1,
    float* __restrict__ hd, float* __restrict__ kbuf,
    unsigned short* __restrict__ mask2, float* __restrict__ Mm,
    float* __restrict__ W1t, float* __restrict__ W2t,
    float* __restrict__ outz)
{
    const int bid = blockIdx.x;
    const int tid = threadIdx.x;
    __shared__ float shbuf[2048];

    if (bid < 1152) {                          // ---- prep
        const int pixblk = bid & 63, iz = bid >> 6;
        const int i = iz >> 1, z = iz & 1;
        const int pix = pixblk * 256 + tid;
        const int hh = pix >> 7, ww = pix & (WW - 1);
        float fc[NC];
#pragma unroll
        for (int c = 0; c < NC; ++c) fc[c] = f[c * NPIX + pix];
        const int qh = hh + i * DIL - PAD;
        const bool vh = (unsigned)qh < HH;
        const int j0 = z * 5;                  // z=0: j 0..4, z=1: j 5..8
        unsigned pmask = 0;
#pragma unroll
        for (int jj = 0; jj < 5; ++jj) {
            int j = j0 + jj;
            if (j < KS) {
                int qw = ww + j * DIL - PAD;
                bool valid = vh & ((unsigned)qw < WW);
                int q = valid ? (qh * WW + qw) : pix;   // safe masked addr
                float s0 = 0.f, s1 = 0.f, s2 = 0.f, s3 = 0.f;
#pragma unroll
                for (int c4 = 0; c4 < 8; ++c4) {
                    float d0 = f[(4 * c4 + 0) * NPIX + q] - fc[4 * c4 + 0];
                    float d1 = f[(4 * c4 + 1) * NPIX + q] - fc[4 * c4 + 1];
                    float d2 = f[(4 * c4 + 2) * NPIX + q] - fc[4 * c4 + 2];
                    float d3 = f[(4 * c4 + 3) * NPIX + q] - fc[4 * c4 + 3];
                    s0 = fmaf(d0, d0, s0); s1 = fmaf(d1, d1, s1);
                    s2 = fmaf(d2, d2, s2); s3 = fmaf(d3, d3, s3);
                }
                float s = (s0 + s1) + (s2 + s3);
                // OOB taps contribute exactly 0 (x zero-padded) -> drop.
                bool live = valid && (s <= SMAX) && !(i == 4 && j == 4);
                if (live) {
                    pmask |= 1u << jj;
                    kbuf[(i * KS + j) * NPIX + pix] = __expf(-0.5f * s);
                }
            }
        }
        // byte ownership (z=low/high) -> no atomics, unconditional: kills poison
        ((unsigned char*)mask2)[2 * (i * NPIX + pix) + z] = (unsigned char)pmask;
        return;
    }

    if (bid < 1664) {                          // ---- dense1 -> hd
        const int r = bid - 1152;
        const int o0 = (r >> 6) * 4;
        const int pix = (r & 63) * 256 + tid;
        if (tid < 128)
            shbuf[tid] = W1[((o0 + (tid >> 5)) * NC + (tid & 31)) * TAPS + 40];
        __syncthreads();
        float x0[NC];
#pragma unroll
        for (int c = 0; c < NC; ++c) x0[c] = x[c * NPIX + pix];
        float a0 = 0.f, a1 = 0.f, a2 = 0.f, a3 = 0.f;
#pragma unroll
        for (int c = 0; c < NC; ++c) {
            float xv = x0[c];
            a0 = fmaf(xv, shbuf[0 * NC + c], a0);
            a1 = fmaf(xv, shbuf[1 * NC + c], a1);
            a2 = fmaf(xv, shbuf[2 * NC + c], a2);
            a3 = fmaf(xv, shbuf[3 * NC + c], a3);
        }
        hd[(o0 + 0) * NPIX + pix] = a0 + b1[o0 + 0];
        hd[(o0 + 1) * NPIX + pix] = a1 + b1[o0 + 1];
        hd[(o0 + 2) * NPIX + pix] = a2 + b1[o0 + 2];
        hd[(o0 + 3) * NPIX + pix] = a3 + b1[o0 + 3];
        return;
    }

    if (bid < 1792) {                          // ---- zero d_out
        float4 z4 = make_float4(0.f, 0.f, 0.f, 0.f);
        for (int t = (bid - 1664) * 256 + tid; t < (NO * NPIX) / 4;
             t += 128 * 256)
            ((float4*)outz)[t] = z4;
        return;
    }

    if (bid < 1873) {                          // ---- M[T] = W2c @ W1[T]
        const int T = bid - 1792;
        float* w2c_l = shbuf;                  // [o*32+c]
        float* w1t_l = shbuf + 1024;           // [c*32+c']
        for (int t = tid; t < 1024; t += 256) {
            w2c_l[t] = W2[t * TAPS + 40];      // t = o*32+c
            w1t_l[t] = W1[t * TAPS + T];       // t = c*32+c'
        }
        __syncthreads();
        for (int idx = tid; idx < 1024; idx += 256) {
            int o = idx >> 5, cp = idx & 31;
            float acc = 0.f;
#pragma unroll
            for (int c = 0; c < NC; ++c)
                acc = fmaf(w2c_l[o * NC + c], w1t_l[c * NC + cp], acc);
            Mm[(T * NO + o) * NC + cp] = acc;
        }
        return;
    }

    // ---- [1873,1937): transpose W1,W2 -> [tap][o][c]
    for (int t = (bid - 1873) * 256 + tid; t < NW; t += 64 * 256) {
        int o = t / (NC * TAPS);
        int r = t - o * (NC * TAPS);
        int c = r / TAPS;
        int tap = r - c * TAPS;
        int d = (tap * NO + o) * NC + c;
        W1t[d] = W1[t];
        W2t[d] = W2[t];
    }
}

// ---------------------------------------------------------------------------
// D2 (back2): second (last) dispatch. out = pre-zeroed, ALL writes atomic ->
// order-independent. Exact expansion with h = hd + hs:
//   role A [0,512):  out += b2 + W2c·hd(p)                       (dense)
//   role B [512,1024): per live tap T at p (q = p+off(T), kv):
//       (C) kv * W2t[T]·hd(q)        -- dense part of h(q)
//       (B) kv * M[T]·x(q)           -- W2c·hs(p), M = W2c@W1[T] precomputed
//       (D) kv * sum_{T' live at q} kv' * W2t[T]·(W1t[T']·x(q+off(T')))
//   (D) uses half-wave LDS staging for the intermediate u = W1t[T']·x
//   (intra-wave LDS producer->consumer: DS ops of a wave are ordered).
// ---------------------------------------------------------------------------
__global__ __launch_bounds__(256) void back2_kernel(
    const float* __restrict__ x, const float* __restrict__ hd,
    const float* __restrict__ kbuf, const unsigned short* __restrict__ mask2,
    const float* __restrict__ Mm, const float* __restrict__ W1t,
    const float* __restrict__ W2t, const float* __restrict__ W2,
    const float* __restrict__ b2, float* __restrict__ out)
{
    const int bid = blockIdx.x;
    const int tid = threadIdx.x;

    if (bid < 512) {                           // ---- role A: dense2 (atomic)
        __shared__ float wsm[4 * NC];
        const int o0 = (bid >> 6) * 4;
        const int pix = (bid & 63) * 256 + tid;
        if (tid < 128)
            wsm[tid] = W2[((o0 + (tid >> 5)) * NC + (tid & 31)) * TAPS + 40];
        __syncthreads();
        float h0[NC];
#pragma unroll
        for (int c = 0; c < NC; ++c) h0[c] = hd[c * NPIX + pix];
        float a0 = 0.f, a1 = 0.f, a2 = 0.f, a3 = 0.f;
#pragma unroll
        for (int c = 0; c < NC; ++c) {
            float hv = h0[c];
            a0 = fmaf(hv, wsm[0 * NC + c], a0);
            a1 = fmaf(hv, wsm[1 * NC + c], a1);
            a2 = fmaf(hv, wsm[2 * NC + c], a2);
            a3 = fmaf(hv, wsm[3 * NC + c], a3);
        }
        atomicAdd(&out[(o0 + 0) * NPIX + pix], a0 + b2[o0 + 0]);
        atomicAdd(&out[(o0 + 1) * NPIX + pix], a1 + b2[o0 + 1]);
        atomicAdd(&out[(o0 + 2) * NPIX + pix], a2 + b2[o0 + 2]);
        atomicAdd(&out[(o0 + 3) * NPIX + pix], a3 + b2[o0 + 3]);
        return;
    }

    // ---- role B: sparse terms. Half-wave (32 lanes) per pixel, 4 pixels ea.
    __shared__ float u_lds[8][NC];
    const int hw = tid >> 5;                   // 0..7
    const int lane = tid & 31;                 // output o / channel c
    const int pbase = (bid - 512) * 32;

    for (int pp = hw; pp < 32; pp += 8) {
        const int p = pbase + pp;
        unsigned long long A0; unsigned A1;
        BUILD_MASK(p, A0, A1);
        while (A0 || A1) {
            int T;
            if (A0) { T = __builtin_ctzll(A0); A0 &= A0 - 1; }
            else    { T = 64 + __builtin_ctz(A1); A1 &= A1 - 1; }
            const int ii = T / KS, jj = T - KS * ii;
            const int q = p + (ii * DIL - PAD) * WW + (jj * DIL - PAD);
            const float kv = kbuf[T * NPIX + p];

            // per-lane rows of W2t[T] and M[T] into registers (reused by (D))
            float w2r[NC], mr[NC];
            {
                const float4* w2p = (const float4*)(W2t + (T * NO + lane) * NC);
                const float4* mp  = (const float4*)(Mm  + (T * NO + lane) * NC);
#pragma unroll
                for (int c4 = 0; c4 < 8; ++c4) {
                    float4 w4 = w2p[c4], m4 = mp[c4];
                    w2r[4 * c4 + 0] = w4.x; w2r[4 * c4 + 1] = w4.y;
                    w2r[4 * c4 + 2] = w4.z; w2r[4 * c4 + 3] = w4.w;
                    mr[4 * c4 + 0] = m4.x; mr[4 * c4 + 1] = m4.y;
                    mr[4 * c4 + 2] = m4.z; mr[4 * c4 + 3] = m4.w;
                }
            }

            // (C) + (B): kv * ( W2t[T]·hd(q) + M[T]·x(q) )
            float dot = 0.f;
#pragma unroll
            for (int c = 0; c < NC; ++c) {
                dot = fmaf(w2r[c], hd[c * NPIX + q], dot);
                dot = fmaf(mr[c],  x[c * NPIX + q],  dot);
            }

            // (D): kv * sum_{T' live at q} kv' * W2t[T]·(W1t[T']·x(q'))
            float dsum = 0.f;
            unsigned long long B0; unsigned B1;
            BUILD_MASK(q, B0, B1);
            while (B0 || B1) {
                int T2;
                if (B0) { T2 = __builtin_ctzll(B0); B0 &= B0 - 1; }
                else    { T2 = 64 + __builtin_ctz(B1); B1 &= B1 - 1; }
                const int i2 = T2 / KS, j2 = T2 - KS * i2;
                const int q2 = q + (i2 * DIL - PAD) * WW + (j2 * DIL - PAD);
                const float kv2 = kbuf[T2 * NPIX + q];
                // u[lane] = sum_c' W1t[T'][lane][c'] * x[c'][q2]
                const float4* w1p =
                    (const float4*)(W1t + (T2 * NO + lane) * NC);
                float u = 0.f;
#pragma unroll
                for (int c4 = 0; c4 < 8; ++c4) {
                    float4 w4 = w1p[c4];
                    u = fmaf(w4.x, x[(4 * c4 + 0) * NPIX + q2], u);
                    u = fmaf(w4.y, x[(4 * c4 + 1) * NPIX + q2], u);
                    u = fmaf(w4.z, x[(4 * c4 + 2) * NPIX + q2], u);
                    u = fmaf(w4.w, x[(4 * c4 + 3) * NPIX + q2], u);
                }
                u_lds[hw][lane] = u;           // intra-half-wave staging
                float dd = 0.f;
#pragma unroll
                for (int c = 0; c < NC; ++c)
                    dd = fmaf(w2r[c], u_lds[hw][c], dd);
                dsum = fmaf(kv2, dd, dsum);
            }
            atomicAdd(&out[lane * NPIX + p], kv * (dot + dsum));
        }
    }
}

// ===========================================================================
// Fallback path A (round-5 proven, 126.9 us): 4 classic dispatches.
// ===========================================================================
__global__ __launch_bounds__(64) void zero_cnt_kernel(unsigned* __restrict__ cnt)
{
    if (threadIdx.x == 0) *cnt = 0u;
}

__device__ __forceinline__ void sparse_body(
    const float* __restrict__ in, const float* __restrict__ Wt,
    const unsigned* __restrict__ cnt, const uint2* __restrict__ list,
    float* __restrict__ out, unsigned gid, unsigned stride)
{
    unsigned n = *cnt;
    if (n > CAP) n = CAP;
    const unsigned total = n * 32u;
    for (unsigned it = gid; it < total; it += stride) {
        unsigned e = it >> 5;
        int o = (int)(it & 31u);
        uint2 me = list[e];
        int pix = (int)(me.x & 16383u);
        int T = (int)(me.x >> 14);
        float kv = __uint_as_float(me.y);
        int ii = T / KS, jj = T - KS * ii;
        int q = pix + (ii * DIL - PAD) * WW + (jj * DIL - PAD);
        const float4* __restrict__ wp =
            (const float4*)(Wt + (T * NO + o) * NC);
        float t0 = 0.f, t1 = 0.f, t2 = 0.f, t3 = 0.f;
#pragma unroll
        for (int c4 = 0; c4 < 8; ++c4) {
            float4 w4 = wp[c4];
            t0 = fmaf(in[(4 * c4 + 0) * NPIX + q], w4.x, t0);
            t1 = fmaf(in[(4 * c4 + 1) * NPIX + q], w4.y, t1);
            t2 = fmaf(in[(4 * c4 + 2) * NPIX + q], w4.z, t2);
            t3 = fmaf(in[(4 * c4 + 3) * NPIX + q], w4.w, t3);
        }
        atomicAdd(&out[o * NPIX + pix], kv * ((t0 + t1) + (t2 + t3)));
    }
}

__global__ __launch_bounds__(256) void front_kernel(
    const float* __restrict__ x, const float* __restrict__ f,
    const float* __restrict__ W1, const float* __restrict__ W2,
    const float* __restrict__ b1,
    float* __restrict__ h, unsigned* __restrict__ cnt,
    uint2* __restrict__ list, float* __restrict__ W1t,
    float* __restrict__ W2t, float* __restrict__ outz)
{
    const int y = blockIdx.y;
    const int tid = threadIdx.x;

    if (y < 41) {
        const int pix = blockIdx.x * 256 + tid;
        const int hh = pix >> 7, ww = pix & (WW - 1);
        float fc[NC];
#pragma unroll
        for (int c = 0; c < NC; ++c) fc[c] = f[c * NPIX + pix];
#pragma unroll
        for (int u = 0; u < 2; ++u) {
            int T = 2 * y + u;
            if (T >= TAPS || T == 40) continue;
            int ii = T / KS, jj = T - KS * ii;
            int qh = hh + ii * DIL - PAD;
            int qw = ww + jj * DIL - PAD;
            bool valid = ((unsigned)qh < HH) & ((unsigned)qw < WW);
            int q = valid ? (qh * WW + qw) : pix;
            float s0 = 0.f, s1 = 0.f, s2 = 0.f, s3 = 0.f;
#pragma unroll
            for (int c4 = 0; c4 < 8; ++c4) {
                float d0 = f[(4 * c4 + 0) * NPIX + q] - fc[4 * c4 + 0];
                float d1 = f[(4 * c4 + 1) * NPIX + q] - fc[4 * c4 + 1];
                float d2 = f[(4 * c4 + 2) * NPIX + q] - fc[4 * c4 + 2];
                float d3 = f[(4 * c4 + 3) * NPIX + q] - fc[4 * c4 + 3];
                s0 = fmaf(d0, d0, s0); s1 = fmaf(d1, d1, s1);
                s2 = fmaf(d2, d2, s2); s3 = fmaf(d3, d3, s3);
            }
            float s = (s0 + s1) + (s2 + s3);
            if (valid && (s <= SMAX)) {
                unsigned idx = atomicAdd(cnt, 1u);
                if (idx < CAP)
                    list[idx] = make_uint2(
                        (unsigned)pix | ((unsigned)T << 14),
                        __float_as_uint(__expf(-0.5f * s)));
            }
        }
        return;
    }

    if (y < 49) {
        const int o0 = (y - 41) * 4;
        __shared__ float wsm[4 * NC];
        if (tid < 128) {
            int o = tid >> 5, c = tid & 31;
            wsm[tid] = W1[((o0 + o) * NC + c) * TAPS + 40];
        }
        __syncthreads();
        const int pix = blockIdx.x * 256 + tid;
        float x0[NC];
#pragma unroll
        for (int c = 0; c < NC; ++c) x0[c] = x[c * NPIX + pix];
        float a0 = 0.f, a1 = 0.f, a2 = 0.f, a3 = 0.f;
#pragma unroll
        for (int c = 0; c < NC; ++c) {
            float xv = x0[c];
            a0 = fmaf(xv, wsm[0 * NC + c], a0);
            a1 = fmaf(xv, wsm[1 * NC + c], a1);
            a2 = fmaf(xv, wsm[2 * NC + c], a2);
            a3 = fmaf(xv, wsm[3 * NC + c], a3);
        }
        h[(o0 + 0) * NPIX + pix] = a0 + b1[o0 + 0];
        h[(o0 + 1) * NPIX + pix] = a1 + b1[o0 + 1];
        h[(o0 + 2) * NPIX + pix] = a2 + b1[o0 + 2];
        h[(o0 + 3) * NPIX + pix] = a3 + b1[o0 + 3];
        return;
    }

    if (y == 49) {
        float4 z = make_float4(0.f, 0.f, 0.f, 0.f);
        for (int t = blockIdx.x * 256 + tid; t < (NO * NPIX) / 4; t += 64 * 256)
            ((float4*)outz)[t] = z;
        return;
    }

    for (int t = blockIdx.x * 256 + tid; t < NW; t += 64 * 256) {
        int o = t / (NC * TAPS);
        int r = t - o * (NC * TAPS);
        int c = r / TAPS;
        int tap = r - c * TAPS;
        int d = (tap * NO + o) * NC + c;
        W1t[d] = W1[t];
        W2t[d] = W2[t];
    }
}

__global__ __launch_bounds__(256) void sparse1_kernel(
    const float* __restrict__ x, const float* __restrict__ W1t,
    const unsigned* __restrict__ cnt, const uint2* __restrict__ list,
    float* __restrict__ h)
{
    sparse_body(x, W1t, cnt, list, h,
                blockIdx.x * 256 + threadIdx.x, gridDim.x * 256);
}

__global__ __launch_bounds__(256) void back_kernel(
    const float* __restrict__ h, const float* __restrict__ W2,
    const float* __restrict__ W2t, const float* __restrict__ b2,
    const unsigned* __restrict__ cnt, const uint2* __restrict__ list,
    float* __restrict__ out)
{
    const int y = blockIdx.y;
    const int tid = threadIdx.x;
    if (y < 8) {
        const int o0 = y * 4;
        __shared__ float wsm[4 * NC];
        if (tid < 128) {
            int o = tid >> 5, c = tid & 31;
            wsm[tid] = W2[((o0 + o) * NC + c) * TAPS + 40];
        }
        __syncthreads();
        const int pix = blockIdx.x * 256 + tid;
        float h0[NC];
#pragma unroll
        for (int c = 0; c < NC; ++c) h0[c] = h[c * NPIX + pix];
        float a0 = 0.f, a1 = 0.f, a2 = 0.f, a3 = 0.f;
#pragma unroll
        for (int c = 0; c < NC; ++c) {
            float hv = h0[c];
            a0 = fmaf(hv, wsm[0 * NC + c], a0);
            a1 = fmaf(hv, wsm[1 * NC + c], a1);
            a2 = fmaf(hv, wsm[2 * NC + c], a2);
            a3 = fmaf(hv, wsm[3 * NC + c], a3);
        }
        atomicAdd(&out[(o0 + 0) * NPIX + pix], a0 + b2[o0 + 0]);
        atomicAdd(&out[(o0 + 1) * NPIX + pix], a1 + b2[o0 + 1]);
        atomicAdd(&out[(o0 + 2) * NPIX + pix], a2 + b2[o0 + 2]);
        atomicAdd(&out[(o0 + 3) * NPIX + pix], a3 + b2[o0 + 3]);
        return;
    }
    sparse_body(h, W2t, cnt, list, out,
                blockIdx.x * 256 + tid, 64 * 256);
}

// ===========================================================================
// Fallback path B (tiny ws): fused per-layer, original W layout.
// ===========================================================================
#define CHUNK 27
#define NCHUNK 3
#define KMIN 1e-6f
__global__ __launch_bounds__(256) void pac_layer_fuse(
    const float* __restrict__ in, const float* __restrict__ f,
    const float* __restrict__ Wt, const float* __restrict__ bias,
    float* __restrict__ out)
{
    __shared__ float wl[NC * CHUNK * 8];
    const int og = blockIdx.y;
    const int pix = blockIdx.x * 256 + threadIdx.x;
    const int h = pix >> 7, w = pix & (WW - 1);
    float acc[8];
#pragma unroll
    for (int i = 0; i < 8; ++i) acc[i] = 0.f;
    float fc[NC];
#pragma unroll
    for (int c = 0; c < NC; ++c) fc[c] = f[c * NPIX + pix];
    for (int ch = 0; ch < NCHUNK; ++ch) {
        __syncthreads();
        for (int idx = threadIdx.x; idx < NC * CHUNK * 8; idx += 256) {
            int t = idx % CHUNK;
            int c = (idx / CHUNK) % NC;
            int o = idx / (CHUNK * NC);
            wl[(c * CHUNK + t) * 8 + o] =
                Wt[(og * 8 + o) * (NC * TAPS) + c * TAPS + ch * CHUNK + t];
        }
        __syncthreads();
        for (int t = 0; t < CHUNK; ++t) {
            int tap = ch * CHUNK + t;
            int qh = h + (tap / KS) * DIL - PAD;
            int qw = w + (tap % KS) * DIL - PAD;
            bool valid = ((unsigned)qh < HH) & ((unsigned)qw < WW);
            int q = qh * WW + qw;
            float s = 0.f;
#pragma unroll
            for (int c = 0; c < NC; ++c) {
                float fn = valid ? f[c * NPIX + q] : 0.f;
                float d = fn - fc[c];
                s = fmaf(d, d, s);
            }
            float kv = __expf(-0.5f * s);
            if (__all((kv < KMIN) | (!valid))) continue;
            const float* wpp = &wl[t * 8];
#pragma unroll 8
            for (int c = 0; c < NC; ++c) {
                float v = valid ? in[c * NPIX + q] : 0.f;
                v *= kv;
#pragma unroll
                for (int o = 0; o < 8; ++o)
                    acc[o] = fmaf(v, wpp[c * CHUNK * 8 + o], acc[o]);
            }
        }
    }
#pragma unroll
    for (int o = 0; o < 8; ++o)
        out[(og * 8 + o) * NPIX + pix] = acc[o] + bias[og * 8 + o];
}

// ---------------------------------------------------------------------------
extern "C" void kernel_launch(void* const* d_in, const int* in_sizes, int n_in,
                              void* d_out, int out_size, void* d_ws, size_t ws_size,
                              hipStream_t stream)
{
    (void)in_sizes; (void)n_in; (void)out_size;
    const float* x  = (const float*)d_in[0];
    const float* f  = (const float*)d_in[1];
    const float* W1 = (const float*)d_in[2];
    const float* b1 = (const float*)d_in[3];
    const float* W2 = (const float*)d_in[4];
    const float* b2 = (const float*)d_in[5];
    float* out = (float*)d_out;

    float* ws = (float*)d_ws;
    // main (2-dispatch) layout
    float* hd   = ws;                                   // NO*NPIX
    float* kbuf = hd + NO * NPIX;                       // TAPS*NPIX
    float* W1t  = kbuf + TAPS * NPIX;                   // NW
    float* W2t  = W1t + NW;                             // NW
    float* Mm   = W2t + NW;                             // TAPS*NO*NC
    unsigned short* mask2 = (unsigned short*)(Mm + TAPS * NO * NC); // KS*NPIX
    const size_t need_main =
        (size_t)(NO * NPIX + TAPS * NPIX + 2 * NW + TAPS * NO * NC) * 4
        + (size_t)KS * NPIX * 2;
    // fallback-A layout
    float* hA   = ws;
    float* W1tA = ws + NO * NPIX;
    float* W2tA = W1tA + NW;
    unsigned* cnt = (unsigned*)(W2tA + NW);
    uint2* list = (uint2*)(cnt + 16);
    const size_t need_fb =
        (size_t)(NO * NPIX + 2 * NW + 16) * 4 + (size_t)CAP * 8;

    if (ws_size >= need_main) {
        front2_kernel<<<dim3(1937), 256, 0, stream>>>(
            x, f, W1, W2, b1, hd, kbuf, mask2, Mm, W1t, W2t, out);
        back2_kernel<<<dim3(1024), 256, 0, stream>>>(
            x, hd, kbuf, mask2, Mm, W1t, W2t, W2, b2, out);
    } else if (ws_size >= need_fb) {
        zero_cnt_kernel<<<dim3(1), 64, 0, stream>>>(cnt);
        front_kernel<<<dim3(64, 51), 256, 0, stream>>>(
            x, f, W1, W2, b1, hA, cnt, list, W1tA, W2tA, out);
        sparse1_kernel<<<dim3(128), 256, 0, stream>>>(x, W1tA, cnt, list, hA);
        back_kernel<<<dim3(64, 9), 256, 0, stream>>>(
            hA, W2, W2tA, b2, cnt, list, out);
    } else {
        float* hbuf = ws;
        pac_layer_fuse<<<dim3(64, 4), 256, 0, stream>>>(x, f, W1, b1, hbuf);
        pac_layer_fuse<<<dim3(64, 4), 256, 0, stream>>>(hbuf, f, W2, b2, out);
    }
}

// Round 8
// 114.107 us; speedup vs baseline: 5.6121x; 1.0539x over previous
//
#include <hip/hip_runtime.h>

#define HH 128
#define WW 128
#define NPIX 16384
#define NC 32
#define NO 32
#define KS 9
#define TAPS 81
#define DIL 2
#define PAD 8
#define SMAX 27.6310211159f   // s <= SMAX <=> exp(-0.5 s) >= 1e-6; dropped-tap bound ~1.4e-5 << tol
#define NW (NO * NC * TAPS)   // 82944
#define CAP 262144            // fallback-A list capacity

// ---------------------------------------------------------------------------
// Per-pixel mask record: 32 bytes, byte iz = i*3+z holds the 3-bit live mask
// for taps j in {3z,3z+1,3z+2} of row i (bytes 27..31 unused/never read).
// Written byte-owned by prep blocks (no atomics), read as 2x uint4 in back2.
// ---------------------------------------------------------------------------
#define BUILD_MASK32(P, M0, M1) do {                                        \
        const uint4* mp_ = (const uint4*)(mask32 + (size_t)(P) * 32);       \
        uint4 ma_ = mp_[0], mb_ = mp_[1];                                   \
        unsigned w_[8] = { ma_.x, ma_.y, ma_.z, ma_.w,                      \
                           mb_.x, mb_.y, mb_.z, mb_.w };                    \
        M0 = 0ull; M1 = 0u;                                                 \
        unsigned m9_[9];                                                    \
        _Pragma("unroll")                                                   \
        for (int i_ = 0; i_ < 9; ++i_) {                                    \
            int k0_ = 3 * i_, k1_ = 3 * i_ + 1, k2_ = 3 * i_ + 2;           \
            unsigned b0_ = (w_[k0_ >> 2] >> ((k0_ & 3) * 8)) & 7u;          \
            unsigned b1_ = (w_[k1_ >> 2] >> ((k1_ & 3) * 8)) & 7u;          \
            unsigned b2_ = (w_[k2_ >> 2] >> ((k2_ & 3) * 8)) & 7u;          \
            m9_[i_] = b0_ | (b1_ << 3) | (b2_ << 6);                        \
        }                                                                   \
        _Pragma("unroll")                                                   \
        for (int i_ = 0; i_ < 7; ++i_)                                      \
            M0 |= (unsigned long long)m9_[i_] << (9 * i_);                  \
        M0 |= (unsigned long long)(m9_[7] & 1u) << 63;                      \
        M1 = (m9_[7] >> 1) | (m9_[8] << 8);                                 \
    } while (0)

// ---------------------------------------------------------------------------
// D1 (front2): ONE dispatch, mutually-independent roles by blockIdx.x:
//   [0,1728)    prep: (i, j-third) per block; 27 x 64 blocks. 128 loads/thd.
//               Byte-owned mask32 write (unconditional: kills ws poison) +
//               kbuf[T][pix] for live taps.
//   [1728,2240) dense1: hd = b1 + W1[.,.,center]·x (exact: kv_center = 1).
//   [2240,2368) zero d_out (D2 accumulates with atomics only).
//   [2368,2449) M[T] = W2c @ W1[T] (81 x 32x32 GEMM in LDS).
//   [2449,2513) transpose W1,W2 -> [tap][o][c].
// ---------------------------------------------------------------------------
__global__ __launch_bounds__(256) void front2_kernel(
    const float* __restrict__ x, const float* __restrict__ f,
    const float* __restrict__ W1, const float* __restrict__ W2,
    const float* __restrict__ b1,
    float* __restrict__ hd, float* __restrict__ kbuf,
    unsigned char* __restrict__ mask32, float* __restrict__ Mm,
    float* __restrict__ W1t, float* __restrict__ W2t,
    float* __restrict__ outz)
{
    const int bid = blockIdx.x;
    const int tid = threadIdx.x;
    __shared__ float shbuf[2048];

    if (bid < 1728) {                          // ---- prep
        const int pixblk = bid & 63, iz = bid >> 6;   // iz = i*3+z, 0..26
        const int i = iz / 3, z = iz - 3 * i;
        const int pix = pixblk * 256 + tid;
        const int hh = pix >> 7, ww = pix & (WW - 1);
        float fc[NC];
#pragma unroll
        for (int c = 0; c < NC; ++c) fc[c] = f[c * NPIX + pix];
        const int qh = hh + i * DIL - PAD;
        const bool vh = (unsigned)qh < HH;
        unsigned pmask = 0;
#pragma unroll
        for (int jj = 0; jj < 3; ++jj) {
            int j = 3 * z + jj;
            int qw = ww + j * DIL - PAD;
            bool valid = vh & ((unsigned)qw < WW);
            int q = valid ? (qh * WW + qw) : pix;   // safe masked addr
            float s0 = 0.f, s1 = 0.f, s2 = 0.f, s3 = 0.f;
#pragma unroll
            for (int c4 = 0; c4 < 8; ++c4) {
                float d0 = f[(4 * c4 + 0) * NPIX + q] - fc[4 * c4 + 0];
                float d1 = f[(4 * c4 + 1) * NPIX + q] - fc[4 * c4 + 1];
                float d2 = f[(4 * c4 + 2) * NPIX + q] - fc[4 * c4 + 2];
                float d3 = f[(4 * c4 + 3) * NPIX + q] - fc[4 * c4 + 3];
                s0 = fmaf(d0, d0, s0); s1 = fmaf(d1, d1, s1);
                s2 = fmaf(d2, d2, s2); s3 = fmaf(d3, d3, s3);
            }
            float s = (s0 + s1) + (s2 + s3);
            // OOB taps contribute exactly 0 (x zero-padded) -> drop exactly.
            bool live = valid && (s <= SMAX) && !(i == 4 && j == 4);
            if (live) {
                pmask |= 1u << jj;
                kbuf[(i * KS + j) * NPIX + pix] = __expf(-0.5f * s);
            }
        }
        mask32[(size_t)pix * 32 + iz] = (unsigned char)pmask;
        return;
    }

    if (bid < 2240) {                          // ---- dense1 -> hd
        const int r = bid - 1728;
        const int o0 = (r >> 6) * 4;
        const int pix = (r & 63) * 256 + tid;
        if (tid < 128)
            shbuf[tid] = W1[((o0 + (tid >> 5)) * NC + (tid & 31)) * TAPS + 40];
        __syncthreads();
        float x0[NC];
#pragma unroll
        for (int c = 0; c < NC; ++c) x0[c] = x[c * NPIX + pix];
        float a0 = 0.f, a1 = 0.f, a2 = 0.f, a3 = 0.f;
#pragma unroll
        for (int c = 0; c < NC; ++c) {
            float xv = x0[c];
            a0 = fmaf(xv, shbuf[0 * NC + c], a0);
            a1 = fmaf(xv, shbuf[1 * NC + c], a1);
            a2 = fmaf(xv, shbuf[2 * NC + c], a2);
            a3 = fmaf(xv, shbuf[3 * NC + c], a3);
        }
        hd[(o0 + 0) * NPIX + pix] = a0 + b1[o0 + 0];
        hd[(o0 + 1) * NPIX + pix] = a1 + b1[o0 + 1];
        hd[(o0 + 2) * NPIX + pix] = a2 + b1[o0 + 2];
        hd[(o0 + 3) * NPIX + pix] = a3 + b1[o0 + 3];
        return;
    }

    if (bid < 2368) {                          // ---- zero d_out
        float4 z4 = make_float4(0.f, 0.f, 0.f, 0.f);
        for (int t = (bid - 2240) * 256 + tid; t < (NO * NPIX) / 4;
             t += 128 * 256)
            ((float4*)outz)[t] = z4;
        return;
    }

    if (bid < 2449) {                          // ---- M[T] = W2c @ W1[T]
        const int T = bid - 2368;
        float* w2c_l = shbuf;                  // [o*32+c]
        float* w1t_l = shbuf + 1024;           // [c*32+c']
        for (int t = tid; t < 1024; t += 256) {
            w2c_l[t] = W2[t * TAPS + 40];      // t = o*32+c
            w1t_l[t] = W1[t * TAPS + T];       // t = c*32+c'
        }
        __syncthreads();
        for (int idx = tid; idx < 1024; idx += 256) {
            int o = idx >> 5, cp = idx & 31;
            float acc = 0.f;
#pragma unroll
            for (int c = 0; c < NC; ++c)
                acc = fmaf(w2c_l[o * NC + c], w1t_l[c * NC + cp], acc);
            Mm[(T * NO + o) * NC + cp] = acc;
        }
        return;
    }

    // ---- [2449,2513): transpose W1,W2 -> [tap][o][c]
    for (int t = (bid - 2449) * 256 + tid; t < NW; t += 64 * 256) {
        int o = t / (NC * TAPS);
        int r = t - o * (NC * TAPS);
        int c = r / TAPS;
        int tap = r - c * TAPS;
        int d = (tap * NO + o) * NC + c;
        W1t[d] = W1[t];
        W2t[d] = W2[t];
    }
}

// ---------------------------------------------------------------------------
// D2 (back2): out = pre-zeroed, ALL writes atomic -> order-independent.
// Exact expansion with h = hd + hs:
//   role A [0,512):   out += b2 + W2c·hd(p)                      (dense)
//   role B [512,2560): ONE pixel per half-wave (was 4 serial in r7 — its 46us
//       4.5%-occupancy tail was the serial mask-chain per pixel). Mask now
//       read as 2x uint4. Per live tap T at p (q = p+off(T), kv):
//       (C) kv * W2t[T]·hd(q)   (B) kv * M[T]·x(q)
//       (D) kv * sum_{T' live at q} kv' * W2t[T]·(W1t[T']·x(q+off(T')))
// ---------------------------------------------------------------------------
__global__ __launch_bounds__(256) void back2_kernel(
    const float* __restrict__ x, const float* __restrict__ hd,
    const float* __restrict__ kbuf, const unsigned char* __restrict__ mask32,
    const float* __restrict__ Mm, const float* __restrict__ W1t,
    const float* __restrict__ W2t, const float* __restrict__ W2,
    const float* __restrict__ b2, float* __restrict__ out)
{
    const int bid = blockIdx.x;
    const int tid = threadIdx.x;

    if (bid < 512) {                           // ---- role A: dense2 (atomic)
        __shared__ float wsm[4 * NC];
        const int o0 = (bid >> 6) * 4;
        const int pix = (bid & 63) * 256 + tid;
        if (tid < 128)
            wsm[tid] = W2[((o0 + (tid >> 5)) * NC + (tid & 31)) * TAPS + 40];
        __syncthreads();
        float h0[NC];
#pragma unroll
        for (int c = 0; c < NC; ++c) h0[c] = hd[c * NPIX + pix];
        float a0 = 0.f, a1 = 0.f, a2 = 0.f, a3 = 0.f;
#pragma unroll
        for (int c = 0; c < NC; ++c) {
            float hv = h0[c];
            a0 = fmaf(hv, wsm[0 * NC + c], a0);
            a1 = fmaf(hv, wsm[1 * NC + c], a1);
            a2 = fmaf(hv, wsm[2 * NC + c], a2);
            a3 = fmaf(hv, wsm[3 * NC + c], a3);
        }
        atomicAdd(&out[(o0 + 0) * NPIX + pix], a0 + b2[o0 + 0]);
        atomicAdd(&out[(o0 + 1) * NPIX + pix], a1 + b2[o0 + 1]);
        atomicAdd(&out[(o0 + 2) * NPIX + pix], a2 + b2[o0 + 2]);
        atomicAdd(&out[(o0 + 3) * NPIX + pix], a3 + b2[o0 + 3]);
        return;
    }

    // ---- role B: one pixel per half-wave; empty masks fall through fast.
    __shared__ float u_lds[8][NC];
    const int hw = tid >> 5;                   // 0..7
    const int lane = tid & 31;                 // output o / channel c
    const int p = (bid - 512) * 8 + hw;

    unsigned long long A0; unsigned A1;
    BUILD_MASK32(p, A0, A1);
    while (A0 || A1) {
        int T;
        if (A0) { T = __builtin_ctzll(A0); A0 &= A0 - 1; }
        else    { T = 64 + __builtin_ctz(A1); A1 &= A1 - 1; }
        const int ii = T / KS, jj = T - KS * ii;
        const int q = p + (ii * DIL - PAD) * WW + (jj * DIL - PAD);
        const float kv = kbuf[T * NPIX + p];

        // per-lane rows of W2t[T] and M[T] into registers (reused by (D))
        float w2r[NC], mr[NC];
        {
            const float4* w2p = (const float4*)(W2t + (T * NO + lane) * NC);
            const float4* mp  = (const float4*)(Mm  + (T * NO + lane) * NC);
#pragma unroll
            for (int c4 = 0; c4 < 8; ++c4) {
                float4 w4 = w2p[c4], m4 = mp[c4];
                w2r[4 * c4 + 0] = w4.x; w2r[4 * c4 + 1] = w4.y;
                w2r[4 * c4 + 2] = w4.z; w2r[4 * c4 + 3] = w4.w;
                mr[4 * c4 + 0] = m4.x; mr[4 * c4 + 1] = m4.y;
                mr[4 * c4 + 2] = m4.z; mr[4 * c4 + 3] = m4.w;
            }
        }

        // (C) + (B): kv * ( W2t[T]·hd(q) + M[T]·x(q) )
        float dot = 0.f;
#pragma unroll
        for (int c = 0; c < NC; ++c) {
            dot = fmaf(w2r[c], hd[c * NPIX + q], dot);
            dot = fmaf(mr[c],  x[c * NPIX + q],  dot);
        }

        // (D): kv * sum_{T' live at q} kv' * W2t[T]·(W1t[T']·x(q'))
        float dsum = 0.f;
        unsigned long long B0; unsigned B1;
        BUILD_MASK32(q, B0, B1);
        while (B0 || B1) {
            int T2;
            if (B0) { T2 = __builtin_ctzll(B0); B0 &= B0 - 1; }
            else    { T2 = 64 + __builtin_ctz(B1); B1 &= B1 - 1; }
            const int i2 = T2 / KS, j2 = T2 - KS * i2;
            const int q2 = q + (i2 * DIL - PAD) * WW + (j2 * DIL - PAD);
            const float kv2 = kbuf[T2 * NPIX + q];
            // u[lane] = sum_c' W1t[T'][lane][c'] * x[c'][q2]
            const float4* w1p = (const float4*)(W1t + (T2 * NO + lane) * NC);
            float u = 0.f;
#pragma unroll
            for (int c4 = 0; c4 < 8; ++c4) {
                float4 w4 = w1p[c4];
                u = fmaf(w4.x, x[(4 * c4 + 0) * NPIX + q2], u);
                u = fmaf(w4.y, x[(4 * c4 + 1) * NPIX + q2], u);
                u = fmaf(w4.z, x[(4 * c4 + 2) * NPIX + q2], u);
                u = fmaf(w4.w, x[(4 * c4 + 3) * NPIX + q2], u);
            }
            u_lds[hw][lane] = u;               // intra-wave DS order
            float dd = 0.f;
#pragma unroll
            for (int c = 0; c < NC; ++c)
                dd = fmaf(w2r[c], u_lds[hw][c], dd);
            dsum = fmaf(kv2, dd, dsum);
        }
        atomicAdd(&out[lane * NPIX + p], kv * (dot + dsum));
    }
}

// ===========================================================================
// Fallback path A (round-5 proven, 126.9 us): 4 classic dispatches.
// ===========================================================================
__global__ __launch_bounds__(64) void zero_cnt_kernel(unsigned* __restrict__ cnt)
{
    if (threadIdx.x == 0) *cnt = 0u;
}

__device__ __forceinline__ void sparse_body(
    const float* __restrict__ in, const float* __restrict__ Wt,
    const unsigned* __restrict__ cnt, const uint2* __restrict__ list,
    float* __restrict__ out, unsigned gid, unsigned stride)
{
    unsigned n = *cnt;
    if (n > CAP) n = CAP;
    const unsigned total = n * 32u;
    for (unsigned it = gid; it < total; it += stride) {
        unsigned e = it >> 5;
        int o = (int)(it & 31u);
        uint2 me = list[e];
        int pix = (int)(me.x & 16383u);
        int T = (int)(me.x >> 14);
        float kv = __uint_as_float(me.y);
        int ii = T / KS, jj = T - KS * ii;
        int q = pix + (ii * DIL - PAD) * WW + (jj * DIL - PAD);
        const float4* __restrict__ wp =
            (const float4*)(Wt + (T * NO + o) * NC);
        float t0 = 0.f, t1 = 0.f, t2 = 0.f, t3 = 0.f;
#pragma unroll
        for (int c4 = 0; c4 < 8; ++c4) {
            float4 w4 = wp[c4];
            t0 = fmaf(in[(4 * c4 + 0) * NPIX + q], w4.x, t0);
            t1 = fmaf(in[(4 * c4 + 1) * NPIX + q], w4.y, t1);
            t2 = fmaf(in[(4 * c4 + 2) * NPIX + q], w4.z, t2);
            t3 = fmaf(in[(4 * c4 + 3) * NPIX + q], w4.w, t3);
        }
        atomicAdd(&out[o * NPIX + pix], kv * ((t0 + t1) + (t2 + t3)));
    }
}

__global__ __launch_bounds__(256) void front_kernel(
    const float* __restrict__ x, const float* __restrict__ f,
    const float* __restrict__ W1, const float* __restrict__ W2,
    const float* __restrict__ b1,
    float* __restrict__ h, unsigned* __restrict__ cnt,
    uint2* __restrict__ list, float* __restrict__ W1t,
    float* __restrict__ W2t, float* __restrict__ outz)
{
    const int y = blockIdx.y;
    const int tid = threadIdx.x;

    if (y < 41) {
        const int pix = blockIdx.x * 256 + tid;
        const int hh = pix >> 7, ww = pix & (WW - 1);
        float fc[NC];
#pragma unroll
        for (int c = 0; c < NC; ++c) fc[c] = f[c * NPIX + pix];
#pragma unroll
        for (int u = 0; u < 2; ++u) {
            int T = 2 * y + u;
            if (T >= TAPS || T == 40) continue;
            int ii = T / KS, jj = T - KS * ii;
            int qh = hh + ii * DIL - PAD;
            int qw = ww + jj * DIL - PAD;
            bool valid = ((unsigned)qh < HH) & ((unsigned)qw < WW);
            int q = valid ? (qh * WW + qw) : pix;
            float s0 = 0.f, s1 = 0.f, s2 = 0.f, s3 = 0.f;
#pragma unroll
            for (int c4 = 0; c4 < 8; ++c4) {
                float d0 = f[(4 * c4 + 0) * NPIX + q] - fc[4 * c4 + 0];
                float d1 = f[(4 * c4 + 1) * NPIX + q] - fc[4 * c4 + 1];
                float d2 = f[(4 * c4 + 2) * NPIX + q] - fc[4 * c4 + 2];
                float d3 = f[(4 * c4 + 3) * NPIX + q] - fc[4 * c4 + 3];
                s0 = fmaf(d0, d0, s0); s1 = fmaf(d1, d1, s1);
                s2 = fmaf(d2, d2, s2); s3 = fmaf(d3, d3, s3);
            }
            float s = (s0 + s1) + (s2 + s3);
            if (valid && (s <= SMAX)) {
                unsigned idx = atomicAdd(cnt, 1u);
                if (idx < CAP)
                    list[idx] = make_uint2(
                        (unsigned)pix | ((unsigned)T << 14),
                        __float_as_uint(__expf(-0.5f * s)));
            }
        }
        return;
    }

    if (y < 49) {
        const int o0 = (y - 41) * 4;
        __shared__ float wsm[4 * NC];
        if (tid < 128) {
            int o = tid >> 5, c = tid & 31;
            wsm[tid] = W1[((o0 + o) * NC + c) * TAPS + 40];
        }
        __syncthreads();
        const int pix = blockIdx.x * 256 + tid;
        float x0[NC];
#pragma unroll
        for (int c = 0; c < NC; ++c) x0[c] = x[c * NPIX + pix];
        float a0 = 0.f, a1 = 0.f, a2 = 0.f, a3 = 0.f;
#pragma unroll
        for (int c = 0; c < NC; ++c) {
            float xv = x0[c];
            a0 = fmaf(xv, wsm[0 * NC + c], a0);
            a1 = fmaf(xv, wsm[1 * NC + c], a1);
            a2 = fmaf(xv, wsm[2 * NC + c], a2);
            a3 = fmaf(xv, wsm[3 * NC + c], a3);
        }
        h[(o0 + 0) * NPIX + pix] = a0 + b1[o0 + 0];
        h[(o0 + 1) * NPIX + pix] = a1 + b1[o0 + 1];
        h[(o0 + 2) * NPIX + pix] = a2 + b1[o0 + 2];
        h[(o0 + 3) * NPIX + pix] = a3 + b1[o0 + 3];
        return;
    }

    if (y == 49) {
        float4 z = make_float4(0.f, 0.f, 0.f, 0.f);
        for (int t = blockIdx.x * 256 + tid; t < (NO * NPIX) / 4; t += 64 * 256)
            ((float4*)outz)[t] = z;
        return;
    }

    for (int t = blockIdx.x * 256 + tid; t < NW; t += 64 * 256) {
        int o = t / (NC * TAPS);
        int r = t - o * (NC * TAPS);
        int c = r / TAPS;
        int tap = r - c * TAPS;
        int d = (tap * NO + o) * NC + c;
        W1t[d] = W1[t];
        W2t[d] = W2[t];
    }
}

__global__ __launch_bounds__(256) void sparse1_kernel(
    const float* __restrict__ x, const float* __restrict__ W1t,
    const unsigned* __restrict__ cnt, const uint2* __restrict__ list,
    float* __restrict__ h)
{
    sparse_body(x, W1t, cnt, list, h,
                blockIdx.x * 256 + threadIdx.x, gridDim.x * 256);
}

__global__ __launch_bounds__(256) void back_kernel(
    const float* __restrict__ h, const float* __restrict__ W2,
    const float* __restrict__ W2t, const float* __restrict__ b2,
    const unsigned* __restrict__ cnt, const uint2* __restrict__ list,
    float* __restrict__ out)
{
    const int y = blockIdx.y;
    const int tid = threadIdx.x;
    if (y < 8) {
        const int o0 = y * 4;
        __shared__ float wsm[4 * NC];
        if (tid < 128) {
            int o = tid >> 5, c = tid & 31;
            wsm[tid] = W2[((o0 + o) * NC + c) * TAPS + 40];
        }
        __syncthreads();
        const int pix = blockIdx.x * 256 + tid;
        float h0[NC];
#pragma unroll
        for (int c = 0; c < NC; ++c) h0[c] = h[c * NPIX + pix];
        float a0 = 0.f, a1 = 0.f, a2 = 0.f, a3 = 0.f;
#pragma unroll
        for (int c = 0; c < NC; ++c) {
            float hv = h0[c];
            a0 = fmaf(hv, wsm[0 * NC + c], a0);
            a1 = fmaf(hv, wsm[1 * NC + c], a1);
            a2 = fmaf(hv, wsm[2 * NC + c], a2);
            a3 = fmaf(hv, wsm[3 * NC + c], a3);
        }
        atomicAdd(&out[(o0 + 0) * NPIX + pix], a0 + b2[o0 + 0]);
        atomicAdd(&out[(o0 + 1) * NPIX + pix], a1 + b2[o0 + 1]);
        atomicAdd(&out[(o0 + 2) * NPIX + pix], a2 + b2[o0 + 2]);
        atomicAdd(&out[(o0 + 3) * NPIX + pix], a3 + b2[o0 + 3]);
        return;
    }
    sparse_body(h, W2t, cnt, list, out,
                blockIdx.x * 256 + tid, 64 * 256);
}

// ===========================================================================
// Fallback path B (tiny ws): fused per-layer, original W layout.
// ===========================================================================
#define CHUNK 27
#define NCHUNK 3
#define KMIN 1e-6f
__global__ __launch_bounds__(256) void pac_layer_fuse(
    const float* __restrict__ in, const float* __restrict__ f,
    const float* __restrict__ Wt, const float* __restrict__ bias,
    float* __restrict__ out)
{
    __shared__ float wl[NC * CHUNK * 8];
    const int og = blockIdx.y;
    const int pix = blockIdx.x * 256 + threadIdx.x;
    const int h = pix >> 7, w = pix & (WW - 1);
    float acc[8];
#pragma unroll
    for (int i = 0; i < 8; ++i) acc[i] = 0.f;
    float fc[NC];
#pragma unroll
    for (int c = 0; c < NC; ++c) fc[c] = f[c * NPIX + pix];
    for (int ch = 0; ch < NCHUNK; ++ch) {
        __syncthreads();
        for (int idx = threadIdx.x; idx < NC * CHUNK * 8; idx += 256) {
            int t = idx % CHUNK;
            int c = (idx / CHUNK) % NC;
            int o = idx / (CHUNK * NC);
            wl[(c * CHUNK + t) * 8 + o] =
                Wt[(og * 8 + o) * (NC * TAPS) + c * TAPS + ch * CHUNK + t];
        }
        __syncthreads();
        for (int t = 0; t < CHUNK; ++t) {
            int tap = ch * CHUNK + t;
            int qh = h + (tap / KS) * DIL - PAD;
            int qw = w + (tap % KS) * DIL - PAD;
            bool valid = ((unsigned)qh < HH) & ((unsigned)qw < WW);
            int q = qh * WW + qw;
            float s = 0.f;
#pragma unroll
            for (int c = 0; c < NC; ++c) {
                float fn = valid ? f[c * NPIX + q] : 0.f;
                float d = fn - fc[c];
                s = fmaf(d, d, s);
            }
            float kv = __expf(-0.5f * s);
            if (__all((kv < KMIN) | (!valid))) continue;
            const float* wpp = &wl[t * 8];
#pragma unroll 8
            for (int c = 0; c < NC; ++c) {
                float v = valid ? in[c * NPIX + q] : 0.f;
                v *= kv;
#pragma unroll
                for (int o = 0; o < 8; ++o)
                    acc[o] = fmaf(v, wpp[c * CHUNK * 8 + o], acc[o]);
            }
        }
    }
#pragma unroll
    for (int o = 0; o < 8; ++o)
        out[(og * 8 + o) * NPIX + pix] = acc[o] + bias[og * 8 + o];
}

// ---------------------------------------------------------------------------
extern "C" void kernel_launch(void* const* d_in, const int* in_sizes, int n_in,
                              void* d_out, int out_size, void* d_ws, size_t ws_size,
                              hipStream_t stream)
{
    (void)in_sizes; (void)n_in; (void)out_size;
    const float* x  = (const float*)d_in[0];
    const float* f  = (const float*)d_in[1];
    const float* W1 = (const float*)d_in[2];
    const float* b1 = (const float*)d_in[3];
    const float* W2 = (const float*)d_in[4];
    const float* b2 = (const float*)d_in[5];
    float* out = (float*)d_out;

    float* ws = (float*)d_ws;
    // main (2-dispatch) layout
    float* hd   = ws;                                   // NO*NPIX
    float* kbuf = hd + NO * NPIX;                       // TAPS*NPIX
    float* W1t  = kbuf + TAPS * NPIX;                   // NW
    float* W2t  = W1t + NW;                             // NW
    float* Mm   = W2t + NW;                             // TAPS*NO*NC
    unsigned char* mask32 = (unsigned char*)(Mm + TAPS * NO * NC); // NPIX*32 B
    const size_t need_main =
        (size_t)(NO * NPIX + TAPS * NPIX + 2 * NW + TAPS * NO * NC) * 4
        + (size_t)NPIX * 32;
    // fallback-A layout
    float* hA   = ws;
    float* W1tA = ws + NO * NPIX;
    float* W2tA = W1tA + NW;
    unsigned* cnt = (unsigned*)(W2tA + NW);
    uint2* list = (uint2*)(cnt + 16);
    const size_t need_fb =
        (size_t)(NO * NPIX + 2 * NW + 16) * 4 + (size_t)CAP * 8;

    if (ws_size >= need_main) {
        front2_kernel<<<dim3(2513), 256, 0, stream>>>(
            x, f, W1, W2, b1, hd, kbuf, mask32, Mm, W1t, W2t, out);
        back2_kernel<<<dim3(2560), 256, 0, stream>>>(
            x, hd, kbuf, mask32, Mm, W1t, W2t, W2, b2, out);
    } else if (ws_size >= need_fb) {
        zero_cnt_kernel<<<dim3(1), 64, 0, stream>>>(cnt);
        front_kernel<<<dim3(64, 51), 256, 0, stream>>>(
            x, f, W1, W2, b1, hA, cnt, list, W1tA, W2tA, out);
        sparse1_kernel<<<dim3(128), 256, 0, stream>>>(x, W1tA, cnt, list, hA);
        back_kernel<<<dim3(64, 9), 256, 0, stream>>>(
            hA, W2, W2tA, b2, cnt, list, out);
    } else {
        float* hbuf = ws;
        pac_layer_fuse<<<dim3(64, 4), 256, 0, stream>>>(x, f, W1, b1, hbuf);
        pac_layer_fuse<<<dim3(64, 4), 256, 0, stream>>>(hbuf, f, W2, b2, out);
    }
}